// Round 1
// 93.544 us; speedup vs baseline: 1.0648x; 1.0648x over previous
//
#include <hip/hip_runtime.h>
#include <math.h>

// Problem constants (fixed by setup_inputs)
#define B_TOTAL 131072
#define K_COMP  64
#define D_DIM   8
#define NC      36
#define NFEAT   96     // K-dim: 64 quad (t_a*t_b all pairs) + 8 linear + 1 const + 23 pad
#define ROWS_PB 256    // rows per block (4 waves x 4 rowtiles x 16)
#define RT_PW   4      // 16-row tiles per wave

// norm_const = -0.5 * D * log(2*pi)
#define NORM_CONST (-7.3515082656373815f)

typedef __attribute__((ext_vector_type(8))) short bf16x8;
typedef __attribute__((ext_vector_type(4))) float f32x4;

static __device__ __forceinline__ unsigned short bf16_rne(float x) {
    unsigned u = __float_as_uint(x);
    u += 0x7FFF + ((u >> 16) & 1);
    return (unsigned short)(u >> 16);
}
static __device__ __forceinline__ float bf16_f32(unsigned short h) {
    return __uint_as_float(((unsigned)h) << 16);
}

// ---------------------------------------------------------------------------
// Precompute (1 block, 64 threads; one component per thread):
//   W = L^-1 (forward substitution), P = W^T W, h = P mu,
//   g = NORM_CONST - sum log L_ii - 0.5 mu^T P mu.
//   psi[e]: e=8a+b (a,b<8): -0.5*P[a][b]; e=64+b: h[b]; e=72: g; else 0.
//   Stored as split bf16: psi_hi = bf16(v), psi_lo = bf16(v - f32(psi_hi)).
// ---------------------------------------------------------------------------
__global__ void mdn_precompute(const float* __restrict__ mu,
                               const float* __restrict__ Lc,
                               unsigned short* __restrict__ psi_hi,
                               unsigned short* __restrict__ psi_lo,
                               float* __restrict__ out) {
    int k = threadIdx.x;
    if (k == 0) out[0] = 0.0f;   // main kernel atomically accumulates here
    if (k >= K_COMP) return;
    const float* Lk = Lc + k * NC;

    float L[D_DIM][D_DIM];
    float W[D_DIM][D_DIM];
#pragma unroll
    for (int i = 0; i < D_DIM; i++)
#pragma unroll
        for (int j = 0; j < D_DIM; j++) { L[i][j] = 0.0f; W[i][j] = 0.0f; }

    float logdet = 0.0f;
    int idx = 0;
#pragma unroll
    for (int i = 0; i < D_DIM; i++)
#pragma unroll
        for (int j = 0; j <= i; j++) {
            float v = Lk[idx++];
            L[i][j] = v;
            if (j == i) logdet += logf(v);
        }

    // W = L^-1 (lower triangular)
#pragma unroll
    for (int j = 0; j < D_DIM; j++) {
        W[j][j] = 1.0f / L[j][j];
#pragma unroll
        for (int i = 0; i < D_DIM; i++) {
            if (i > j) {
                float acc = 0.0f;
#pragma unroll
                for (int m = 0; m < D_DIM; m++)
                    if (m >= j && m < i) acc += L[i][m] * W[m][j];
                W[i][j] = -acc / L[i][i];
            }
        }
    }

    // P = W^T W
    float P[D_DIM][D_DIM];
#pragma unroll
    for (int a = 0; a < D_DIM; a++)
#pragma unroll
        for (int b = 0; b < D_DIM; b++) {
            float acc = 0.0f;
#pragma unroll
            for (int m = 0; m < D_DIM; m++) acc += W[m][a] * W[m][b];
            P[a][b] = acc;
        }

    float h[D_DIM];
    float qf = 0.0f;
#pragma unroll
    for (int i = 0; i < D_DIM; i++) {
        float acc = 0.0f;
#pragma unroll
        for (int j = 0; j < D_DIM; j++) acc += P[i][j] * mu[k * D_DIM + j];
        h[i] = acc;
        qf += mu[k * D_DIM + i] * acc;
    }
    float g = NORM_CONST - logdet - 0.5f * qf;

    float psi[NFEAT];
#pragma unroll
    for (int e = 0; e < NFEAT; e++) psi[e] = 0.0f;
#pragma unroll
    for (int a = 0; a < D_DIM; a++)
#pragma unroll
        for (int b = 0; b < D_DIM; b++) psi[8 * a + b] = -0.5f * P[a][b];
#pragma unroll
    for (int b = 0; b < D_DIM; b++) psi[64 + b] = h[b];
    psi[72] = g;

    unsigned short* oh = psi_hi + k * NFEAT;
    unsigned short* ol = psi_lo + k * NFEAT;
#pragma unroll
    for (int e = 0; e < NFEAT; e++) {
        unsigned short hi = bf16_rne(psi[e]);
        oh[e] = hi;
        ol[e] = bf16_rne(psi[e] - bf16_f32(hi));
    }
}

// ---------------------------------------------------------------------------
// Main kernel, SWAPPED operand roles vs v1:
//   A = psi (comp-major): A[m][k] = psi[16*mt + m][32*ks + 8q + j] -> per-wave
//       constant, hoisted into 96 VGPRs (24 x bf16x8) before the row loop.
//   B = row features:     B[k][col=n] = phi[row0+n][32*ks + 8q + j], built
//       per tile from t (identical formulas to v1's A-build).
//   Contraction index (features, same order) unchanged -> MFMA results are
//   bitwise identical to v1; only the output layout moves.
//   C/D: col = lane&15 = batch row (row0+n); row = 4q+reg = comp 16mt+4q+reg.
//   => each lane holds 16 of 64 comps in registers; lanes n, n^16, n^32, n^48
//      hold the rest -> LSE = 15 local fmax + 2 shfl_xor (vs 8-step butterfly).
//   => pi[row][16mt+4q .. +3] is one float4 per mt (4 vec loads vs 16 scalar).
// __launch_bounds__(256,2): VGPR cap 256 (v1's (256,4) cap of 128 forced the
// ~200-reg unrolled body into scratch).
// ---------------------------------------------------------------------------
__global__ __launch_bounds__(256, 2) void mdn_main(
        const float* __restrict__ pi,
        const unsigned short* __restrict__ psi_hi,
        const unsigned short* __restrict__ psi_lo,
        const float* __restrict__ target,
        float* __restrict__ out) {
    const int tid = threadIdx.x;
    const int lane = tid & 63;
    const int w = tid >> 6;
    const int q = lane >> 4;
    const int n = lane & 15;
    const int rowbase = blockIdx.x * ROWS_PB;

    __shared__ float Tl[ROWS_PB * D_DIM];   // 8 KB
    {
        const float4* src = (const float4*)(target + (size_t)rowbase * D_DIM);
        float4* dst = (float4*)Tl;
        dst[tid] = src[tid];                 // 512 float4 total, 2 per thread
        dst[tid + 256] = src[tid + 256];
    }

    // Hoist psi A-fragments (per-wave constants; L2-resident, 24 x 16B loads).
    // A-frag layout: lane(q,n) holds A[m=n][k=8q+j] of the 16x32 k-step tile.
    bf16x8 Ah[4][3], Al[4][3];
#pragma unroll
    for (int mt = 0; mt < 4; mt++)
#pragma unroll
        for (int ks = 0; ks < 3; ks++) {
            const int off = (16 * mt + n) * NFEAT + 32 * ks + 8 * q;
            Ah[mt][ks] = *(const bf16x8*)(psi_hi + off);
            Al[mt][ks] = *(const bf16x8*)(psi_lo + off);
        }

    __syncthreads();

    float lacc = 0.0f;

#pragma unroll 2
    for (int r = 0; r < RT_PW; r++) {
        const int row0 = w * (RT_PW * 16) + r * 16;   // local row of tile origin
        const int grow = rowbase + row0 + n;          // this lane's batch row

        // pi for my output comps {16mt+4q+reg}: one float4 per mt
        f32x4 pv4[4];
#pragma unroll
        for (int mt = 0; mt < 4; mt++)
            pv4[mt] = *(const f32x4*)(pi + (size_t)grow * K_COMP + 16 * mt + 4 * q);

        // my B-col t-values
        const f32x4* trow = (const f32x4*)(Tl + (row0 + n) * D_DIM);
        f32x4 tlo = trow[0], thi = trow[1];
        float tv[D_DIM] = {tlo[0], tlo[1], tlo[2], tlo[3],
                           thi[0], thi[1], thi[2], thi[3]};

        // t_a selects: a = 4*ks + q  (branch-free select tree, no dyn index)
        float ta0 = (q & 2) ? ((q & 1) ? tlo[3] : tlo[2]) : ((q & 1) ? tlo[1] : tlo[0]);
        float ta1 = (q & 2) ? ((q & 1) ? thi[3] : thi[2]) : ((q & 1) ? thi[1] : thi[0]);

        bf16x8 Bh[3], Bl[3];
#pragma unroll
        for (int j = 0; j < D_DIM; j++) {
            float f0 = ta0 * tv[j];
            unsigned short h0 = bf16_rne(f0);
            Bh[0][j] = (short)h0;
            Bl[0][j] = (short)bf16_rne(f0 - bf16_f32(h0));

            float f1 = ta1 * tv[j];
            unsigned short h1 = bf16_rne(f1);
            Bh[1][j] = (short)h1;
            Bl[1][j] = (short)bf16_rne(f1 - bf16_f32(h1));

            float f2 = (q == 0) ? tv[j] : ((q == 1 && j == 0) ? 1.0f : 0.0f);
            unsigned short h2 = bf16_rne(f2);
            Bh[2][j] = (short)h2;
            Bl[2][j] = (short)bf16_rne(f2 - bf16_f32(h2));
        }

        // Split-bf16 fp32 emulation: psi_hi*b_hi + psi_lo*b_hi + psi_hi*b_lo
        // (same three product sets, same k order -> bitwise same as v1)
        f32x4 acc[4];
#pragma unroll
        for (int mt = 0; mt < 4; mt++) {
            f32x4 a = {0.0f, 0.0f, 0.0f, 0.0f};
#pragma unroll
            for (int ks = 0; ks < 3; ks++) {
                a = __builtin_amdgcn_mfma_f32_16x16x32_bf16(Ah[mt][ks], Bh[ks], a, 0, 0, 0);
                a = __builtin_amdgcn_mfma_f32_16x16x32_bf16(Al[mt][ks], Bh[ks], a, 0, 0, 0);
                a = __builtin_amdgcn_mfma_f32_16x16x32_bf16(Ah[mt][ks], Bl[ks], a, 0, 0, 0);
            }
            acc[mt] = a;
        }

        // LSE over 64 comps for batch row grow:
        // 16 comps local (mt,reg), remaining in lanes with q^1, q^2 -> 2 shfls.
        float m0 = fmaxf(fmaxf(acc[0][0], acc[0][1]), fmaxf(acc[0][2], acc[0][3]));
        float m1 = fmaxf(fmaxf(acc[1][0], acc[1][1]), fmaxf(acc[1][2], acc[1][3]));
        float m2 = fmaxf(fmaxf(acc[2][0], acc[2][1]), fmaxf(acc[2][2], acc[2][3]));
        float m3 = fmaxf(fmaxf(acc[3][0], acc[3][1]), fmaxf(acc[3][2], acc[3][3]));
        float mrow = fmaxf(fmaxf(m0, m1), fmaxf(m2, m3));
        mrow = fmaxf(mrow, __shfl_xor(mrow, 16));
        mrow = fmaxf(mrow, __shfl_xor(mrow, 32));

        float s = 0.0f;
#pragma unroll
        for (int mt = 0; mt < 4; mt++) {
            s += (pv4[mt][0] + 1e-10f) * __expf(acc[mt][0] - mrow);
            s += (pv4[mt][1] + 1e-10f) * __expf(acc[mt][1] - mrow);
            s += (pv4[mt][2] + 1e-10f) * __expf(acc[mt][2] - mrow);
            s += (pv4[mt][3] + 1e-10f) * __expf(acc[mt][3] - mrow);
        }
        s += __shfl_xor(s, 16);
        s += __shfl_xor(s, 32);

        if (q == 0) lacc += mrow + __logf(s);   // count each row once
    }

    // block reduction -> one atomic
#pragma unroll
    for (int off = 32; off > 0; off >>= 1) lacc += __shfl_down(lacc, off);
    __shared__ float wsum[4];
    if (lane == 0) wsum[w] = lacc;
    __syncthreads();
    if (tid == 0) {
        atomicAdd(out, (wsum[0] + wsum[1] + wsum[2] + wsum[3]) * (-1.0f / (float)B_TOTAL));
    }
}

extern "C" void kernel_launch(void* const* d_in, const int* in_sizes, int n_in,
                              void* d_out, int out_size, void* d_ws, size_t ws_size,
                              hipStream_t stream) {
    const float* pi  = (const float*)d_in[0];
    const float* mu  = (const float*)d_in[1];
    const float* Lc  = (const float*)d_in[2];
    const float* tgt = (const float*)d_in[3];
    float* out = (float*)d_out;

    unsigned short* psi_hi = (unsigned short*)d_ws;                       // 64*96*2 B
    unsigned short* psi_lo = (unsigned short*)((char*)d_ws + K_COMP * NFEAT * 2);

    mdn_precompute<<<1, 64, 0, stream>>>(mu, Lc, psi_hi, psi_lo, out);
    mdn_main<<<B_TOTAL / ROWS_PB, 256, 0, stream>>>(pi, psi_hi, psi_lo, tgt, out);
}

// Round 2
// 91.572 us; speedup vs baseline: 1.0878x; 1.0215x over previous
//
#include <hip/hip_runtime.h>
#include <math.h>

// Problem constants (fixed by setup_inputs)
#define B_TOTAL 131072
#define K_COMP  64
#define D_DIM   8
#define NC      36
#define NFEAT   96     // K-dim: 64 quad (t_a*t_b all pairs) + 8 linear + 1 const + 23 pad
#define NFP     104    // padded LDS row stride (shorts) for psi, spreads banks
#define ROWS_PB 256    // rows per block (4 waves x 4 rowtiles x 16)
#define RT_PW   4      // 16-row tiles per wave

// norm_const = -0.5 * D * log(2*pi)
#define NORM_CONST (-7.3515082656373815f)

typedef __attribute__((ext_vector_type(8))) short bf16x8;
typedef __attribute__((ext_vector_type(4))) float f32x4;

static __device__ __forceinline__ unsigned short bf16_rne(float x) {
    unsigned u = __float_as_uint(x);
    u += 0x7FFF + ((u >> 16) & 1);
    return (unsigned short)(u >> 16);
}
static __device__ __forceinline__ float bf16_f32(unsigned short h) {
    return __uint_as_float(((unsigned)h) << 16);
}

// ---------------------------------------------------------------------------
// Fully fused kernel. v2 (round 1) was two dispatches: a 1-block precompute
// writing psi to global workspace, then the MFMA main kernel. The precompute's
// timeline cost was almost pure launch/serialization (~3-5 us in the graph),
// while main sits at its HBM floor (~7 us for the mandatory 37.5 MB of
// pi+target). v3 fuses: every block redundantly computes all 64 components'
// psi (tid<64, one comp per thread; identical float ops in every block ->
// bitwise-identical psi) into LDS, then runs the identical MFMA pipeline with
// A-fragments served from LDS instead of global. Workspace is unused; out is
// zeroed by a 4-byte hipMemsetAsync.
//
//   A = psi (comp-major), per-wave constant, hoisted to 96 VGPRs.
//   B = row features built from t (branch-free), split-bf16.
//   acc = Ahi*Bhi + Alo*Bhi + Ahi*Blo  (fp32 emulation, same order as v1/v2
//   -> bitwise-identical MFMA results).
//   C/D: col = lane&15 = batch row; row = 4q+reg = comp 16mt+4q+reg.
//   LSE: 15 local fmax/adds + 2 shfl_xor (comps split across q-groups).
// ---------------------------------------------------------------------------
__global__ __launch_bounds__(256, 2) void mdn_fused(
        const float* __restrict__ pi,
        const float* __restrict__ mu,
        const float* __restrict__ Lc,
        const float* __restrict__ target,
        float* __restrict__ out) {
    const int tid = threadIdx.x;
    const int lane = tid & 63;
    const int w = tid >> 6;
    const int q = lane >> 4;
    const int n = lane & 15;
    const int rowbase = blockIdx.x * ROWS_PB;

    __shared__ alignas(16) unsigned short psiH[K_COMP * NFP];  // 13 KB
    __shared__ alignas(16) unsigned short psiL[K_COMP * NFP];  // 13 KB
    __shared__ float Tl[ROWS_PB * D_DIM];                      // 8 KB

    // stage target rows for this block (all 256 threads, 2 x float4 each)
    {
        const float4* src = (const float4*)(target + (size_t)rowbase * D_DIM);
        float4* dst = (float4*)Tl;
        dst[tid] = src[tid];
        dst[tid + 256] = src[tid + 256];
    }

    // ---- per-component psi: wave 0 only, one component per thread ----
    // (identical arithmetic to the old mdn_precompute kernel -> same bits)
    if (tid < K_COMP) {
        const int k = tid;
        const float* Lk = Lc + k * NC;

        float L[D_DIM][D_DIM];
        float W[D_DIM][D_DIM];
#pragma unroll
        for (int i = 0; i < D_DIM; i++)
#pragma unroll
            for (int j = 0; j < D_DIM; j++) { L[i][j] = 0.0f; W[i][j] = 0.0f; }

        float logdet = 0.0f;
        int idx = 0;
#pragma unroll
        for (int i = 0; i < D_DIM; i++)
#pragma unroll
            for (int j = 0; j <= i; j++) {
                float v = Lk[idx++];
                L[i][j] = v;
                if (j == i) logdet += logf(v);
            }

        // W = L^-1 (lower triangular, forward substitution)
#pragma unroll
        for (int j = 0; j < D_DIM; j++) {
            W[j][j] = 1.0f / L[j][j];
#pragma unroll
            for (int i = 0; i < D_DIM; i++) {
                if (i > j) {
                    float acc = 0.0f;
#pragma unroll
                    for (int m = 0; m < D_DIM; m++)
                        if (m >= j && m < i) acc += L[i][m] * W[m][j];
                    W[i][j] = -acc / L[i][i];
                }
            }
        }

        // P = W^T W
        float P[D_DIM][D_DIM];
#pragma unroll
        for (int a = 0; a < D_DIM; a++)
#pragma unroll
            for (int b = 0; b < D_DIM; b++) {
                float acc = 0.0f;
#pragma unroll
                for (int m = 0; m < D_DIM; m++) acc += W[m][a] * W[m][b];
                P[a][b] = acc;
            }

        float h[D_DIM];
        float qf = 0.0f;
#pragma unroll
        for (int i = 0; i < D_DIM; i++) {
            float acc = 0.0f;
#pragma unroll
            for (int j = 0; j < D_DIM; j++) acc += P[i][j] * mu[k * D_DIM + j];
            h[i] = acc;
            qf += mu[k * D_DIM + i] * acc;
        }
        float g = NORM_CONST - logdet - 0.5f * qf;

        float psi[NFEAT];
#pragma unroll
        for (int e = 0; e < NFEAT; e++) psi[e] = 0.0f;
#pragma unroll
        for (int a = 0; a < D_DIM; a++)
#pragma unroll
            for (int b = 0; b < D_DIM; b++) psi[8 * a + b] = -0.5f * P[a][b];
#pragma unroll
        for (int b = 0; b < D_DIM; b++) psi[64 + b] = h[b];
        psi[72] = g;

        unsigned short* oh = psiH + k * NFP;
        unsigned short* ol = psiL + k * NFP;
#pragma unroll
        for (int e = 0; e < NFEAT; e++) {
            unsigned short hi = bf16_rne(psi[e]);
            oh[e] = hi;
            ol[e] = bf16_rne(psi[e] - bf16_f32(hi));
        }
    }

    __syncthreads();

    // Hoist psi A-fragments from LDS (per-wave constants, 24 x ds_read_b128).
    // lane(q,n) holds A[m=n][kfeat=8q+j] of each 16x32 k-step tile.
    bf16x8 Ah[4][3], Al[4][3];
#pragma unroll
    for (int mt = 0; mt < 4; mt++)
#pragma unroll
        for (int ks = 0; ks < 3; ks++) {
            const int off = (16 * mt + n) * NFP + 32 * ks + 8 * q;
            Ah[mt][ks] = *(const bf16x8*)(psiH + off);
            Al[mt][ks] = *(const bf16x8*)(psiL + off);
        }

    float lacc = 0.0f;

#pragma unroll 2
    for (int r = 0; r < RT_PW; r++) {
        const int row0 = w * (RT_PW * 16) + r * 16;   // local row of tile origin
        const int grow = rowbase + row0 + n;          // this lane's batch row

        // pi for my output comps {16mt+4q+reg}: one float4 per mt
        f32x4 pv4[4];
#pragma unroll
        for (int mt = 0; mt < 4; mt++)
            pv4[mt] = *(const f32x4*)(pi + (size_t)grow * K_COMP + 16 * mt + 4 * q);

        // my B-col t-values
        const f32x4* trow = (const f32x4*)(Tl + (row0 + n) * D_DIM);
        f32x4 tlo = trow[0], thi = trow[1];
        float tv[D_DIM] = {tlo[0], tlo[1], tlo[2], tlo[3],
                           thi[0], thi[1], thi[2], thi[3]};

        // t_a selects: a = 4*ks + q  (branch-free select tree, no dyn index)
        float ta0 = (q & 2) ? ((q & 1) ? tlo[3] : tlo[2]) : ((q & 1) ? tlo[1] : tlo[0]);
        float ta1 = (q & 2) ? ((q & 1) ? thi[3] : thi[2]) : ((q & 1) ? thi[1] : thi[0]);

        bf16x8 Bh[3], Bl[3];
#pragma unroll
        for (int j = 0; j < D_DIM; j++) {
            float f0 = ta0 * tv[j];
            unsigned short h0 = bf16_rne(f0);
            Bh[0][j] = (short)h0;
            Bl[0][j] = (short)bf16_rne(f0 - bf16_f32(h0));

            float f1 = ta1 * tv[j];
            unsigned short h1 = bf16_rne(f1);
            Bh[1][j] = (short)h1;
            Bl[1][j] = (short)bf16_rne(f1 - bf16_f32(h1));

            float f2 = (q == 0) ? tv[j] : ((q == 1 && j == 0) ? 1.0f : 0.0f);
            unsigned short h2 = bf16_rne(f2);
            Bh[2][j] = (short)h2;
            Bl[2][j] = (short)bf16_rne(f2 - bf16_f32(h2));
        }

        // Split-bf16 fp32 emulation: psi_hi*b_hi + psi_lo*b_hi + psi_hi*b_lo
        f32x4 acc[4];
#pragma unroll
        for (int mt = 0; mt < 4; mt++) {
            f32x4 a = {0.0f, 0.0f, 0.0f, 0.0f};
#pragma unroll
            for (int ks = 0; ks < 3; ks++) {
                a = __builtin_amdgcn_mfma_f32_16x16x32_bf16(Ah[mt][ks], Bh[ks], a, 0, 0, 0);
                a = __builtin_amdgcn_mfma_f32_16x16x32_bf16(Al[mt][ks], Bh[ks], a, 0, 0, 0);
                a = __builtin_amdgcn_mfma_f32_16x16x32_bf16(Ah[mt][ks], Bl[ks], a, 0, 0, 0);
            }
            acc[mt] = a;
        }

        // LSE over 64 comps for batch row grow:
        // 16 comps local (mt,reg), rest in lanes q^1, q^2 -> 2 shfls.
        float m0 = fmaxf(fmaxf(acc[0][0], acc[0][1]), fmaxf(acc[0][2], acc[0][3]));
        float m1 = fmaxf(fmaxf(acc[1][0], acc[1][1]), fmaxf(acc[1][2], acc[1][3]));
        float m2 = fmaxf(fmaxf(acc[2][0], acc[2][1]), fmaxf(acc[2][2], acc[2][3]));
        float m3 = fmaxf(fmaxf(acc[3][0], acc[3][1]), fmaxf(acc[3][2], acc[3][3]));
        float mrow = fmaxf(fmaxf(m0, m1), fmaxf(m2, m3));
        mrow = fmaxf(mrow, __shfl_xor(mrow, 16));
        mrow = fmaxf(mrow, __shfl_xor(mrow, 32));

        float s = 0.0f;
#pragma unroll
        for (int mt = 0; mt < 4; mt++) {
            s += (pv4[mt][0] + 1e-10f) * __expf(acc[mt][0] - mrow);
            s += (pv4[mt][1] + 1e-10f) * __expf(acc[mt][1] - mrow);
            s += (pv4[mt][2] + 1e-10f) * __expf(acc[mt][2] - mrow);
            s += (pv4[mt][3] + 1e-10f) * __expf(acc[mt][3] - mrow);
        }
        s += __shfl_xor(s, 16);
        s += __shfl_xor(s, 32);

        if (q == 0) lacc += mrow + __logf(s);   // count each row once
    }

    // block reduction -> one atomic
#pragma unroll
    for (int off = 32; off > 0; off >>= 1) lacc += __shfl_down(lacc, off);
    __shared__ float wsum[4];
    if (lane == 0) wsum[w] = lacc;
    __syncthreads();
    if (tid == 0) {
        atomicAdd(out, (wsum[0] + wsum[1] + wsum[2] + wsum[3]) * (-1.0f / (float)B_TOTAL));
    }
}

extern "C" void kernel_launch(void* const* d_in, const int* in_sizes, int n_in,
                              void* d_out, int out_size, void* d_ws, size_t ws_size,
                              hipStream_t stream) {
    const float* pi  = (const float*)d_in[0];
    const float* mu  = (const float*)d_in[1];
    const float* Lc  = (const float*)d_in[2];
    const float* tgt = (const float*)d_in[3];
    float* out = (float*)d_out;

    // out is accumulated atomically by mdn_fused; zero it first (tiny,
    // graph-capturable async memset -- replaces the old 1-block precompute
    // dispatch whose timeline cost was pure launch serialization).
    hipMemsetAsync(out, 0, sizeof(float), stream);
    mdn_fused<<<B_TOTAL / ROWS_PB, 256, 0, stream>>>(pi, mu, Lc, tgt, out);
}